// Round 1
// baseline (686.637 us; speedup 1.0000x reference)
//
#include <hip/hip_runtime.h>
#include <hip/hip_bf16.h>
#include <stdint.h>

#define B_ 16
#define N_ 64
#define S_ 4096
#define C_ 384
#define H_ 6
#define DH_ 64
#define SCALE_ 0.125f

typedef __attribute__((ext_vector_type(8))) short bf16x8;
typedef __attribute__((ext_vector_type(4))) float f32x4;

__device__ __forceinline__ unsigned short f2bf(float x) {
    union { float f; unsigned u; } v; v.f = x;
    unsigned r = v.u + 0x7FFFu + ((v.u >> 16) & 1u);
    return (unsigned short)(r >> 16);
}
__device__ __forceinline__ float bf2f(unsigned short b) {
    union { unsigned u; float f; } v; v.u = ((unsigned)b) << 16; return v.f;
}

// ---------------------------------------------------------------------------
// K1: q[b,n,c] = SCALE * sum_c' query[b,n,c'] * Wq[c,c']   (fp32, SCALE folded)
// ---------------------------------------------------------------------------
__global__ __launch_bounds__(384) void qproj_kernel(const float* __restrict__ query,
                                                    const float* __restrict__ Wq,
                                                    float* __restrict__ qout) {
    __shared__ float row[C_];
    int bn = blockIdx.x;          // b*64+n
    int t = threadIdx.x;          // output feature j
    row[t] = query[(size_t)bn * C_ + t];
    __syncthreads();
    const float4* w4 = (const float4*)(Wq + (size_t)t * C_);
    const float4* r4 = (const float4*)row;
    float acc = 0.f;
#pragma unroll 8
    for (int i = 0; i < C_ / 4; ++i) {
        float4 a = r4[i]; float4 w = w4[i];
        acc += a.x * w.x + a.y * w.y + a.z * w.z + a.w * w.w;
    }
    qout[(size_t)bn * C_ + t] = acc * SCALE_;
}

// ---------------------------------------------------------------------------
// K2: qk[b,h,n,c] = sum_d q[b,n,h*64+d] * Wk[h*64+d, c]    (fp32)
// attn[n,s] = sum_c qk[n,c]*key[s,c]  == SCALE * q.k  (k never materialized)
// ---------------------------------------------------------------------------
__global__ __launch_bounds__(384) void qk_kernel(const float* __restrict__ q,
                                                 const float* __restrict__ Wk,
                                                 float* __restrict__ qk) {
    __shared__ float qh[DH_];
    int n = blockIdx.x, h = blockIdx.y, b = blockIdx.z;
    int t = threadIdx.x;          // output channel c
    if (t < DH_) qh[t] = q[((size_t)(b * N_ + n)) * C_ + h * DH_ + t];
    __syncthreads();
    float acc = 0.f;
    const float* wrow = Wk + (size_t)h * DH_ * C_ + t;   // Wk[(h*64+d)*C + t]
#pragma unroll 8
    for (int d = 0; d < DH_; ++d) acc += qh[d] * wrow[(size_t)d * C_];
    qk[((size_t)(b * H_ + h) * N_ + n) * C_ + t] = acc;
}

// ---------------------------------------------------------------------------
// K3: logits GEMM [64n x 256t, K=384] fp32 + column argmax -> idx[b,h,s]
// thread tile 8n x 8t; LDS transposed staging (As stride 68, Bs stride 256)
// ---------------------------------------------------------------------------
#define TT 256
#define KK 32
#define AS_STR 68
__global__ __launch_bounds__(256) void attn_kernel(const float* __restrict__ qk,
                                                   const float* __restrict__ key,
                                                   unsigned int* __restrict__ idx) {
    __shared__ float smem[KK * AS_STR + KK * TT];   // 41472 B
    float* As = smem;                // [KK][AS_STR], valid [.][64]
    float* Bs = smem + KK * AS_STR;  // [KK][TT]
    int tid = threadIdx.x;
    int s0 = blockIdx.x * TT;
    int h = blockIdx.y, b = blockIdx.z;
    const float* qkh = qk + (size_t)(b * H_ + h) * N_ * C_;
    const float* keyc = key + ((size_t)b * S_ + s0) * C_;
    int nt = tid & 7, tt = tid >> 3;
    int ns = tid >> 2, qs = tid & 3;

    float acc[8][8];
#pragma unroll
    for (int i = 0; i < 8; ++i)
#pragma unroll
        for (int j = 0; j < 8; ++j) acc[i][j] = 0.f;

    for (int kc = 0; kc < C_; kc += KK) {
        __syncthreads();
        // stage As: transpose qk[64][kc..kc+31] -> As[k][n]
#pragma unroll
        for (int half = 0; half < 2; ++half) {
            float4 v = *(const float4*)(qkh + (size_t)ns * C_ + kc + qs * 8 + half * 4);
            int kbase = qs * 8 + half * 4;
            As[(kbase + 0) * AS_STR + ns] = v.x;
            As[(kbase + 1) * AS_STR + ns] = v.y;
            As[(kbase + 2) * AS_STR + ns] = v.z;
            As[(kbase + 3) * AS_STR + ns] = v.w;
        }
        // stage Bs: transpose key[256][kc..kc+31] -> Bs[k][t]
#pragma unroll
        for (int j = 0; j < 8; ++j) {
            float4 v = *(const float4*)(keyc + (size_t)tid * C_ + kc + j * 4);
            Bs[(j * 4 + 0) * TT + tid] = v.x;
            Bs[(j * 4 + 1) * TT + tid] = v.y;
            Bs[(j * 4 + 2) * TT + tid] = v.z;
            Bs[(j * 4 + 3) * TT + tid] = v.w;
        }
        __syncthreads();
#pragma unroll 4
        for (int k = 0; k < KK; ++k) {
            float a[8], bb[8];
            *(float4*)&a[0] = *(float4*)&As[k * AS_STR + nt * 8];
            *(float4*)&a[4] = *(float4*)&As[k * AS_STR + nt * 8 + 4];
            *(float4*)&bb[0] = *(float4*)&Bs[k * TT + tt * 8];
            *(float4*)&bb[4] = *(float4*)&Bs[k * TT + tt * 8 + 4];
#pragma unroll
            for (int i = 0; i < 8; ++i)
#pragma unroll
                for (int j = 0; j < 8; ++j) acc[i][j] += a[i] * bb[j];
        }
    }
    __syncthreads();
    // per-thread argmax over its 8 n's (strict > => first-index ties, np semantics)
    float* red_m = smem;                                   // [8][TT]
    unsigned int* red_i = (unsigned int*)(smem + 8 * TT);  // [8][TT]
#pragma unroll
    for (int j = 0; j < 8; ++j) {
        float best = acc[0][j]; int bi = nt * 8;
#pragma unroll
        for (int i = 1; i < 8; ++i)
            if (acc[i][j] > best) { best = acc[i][j]; bi = nt * 8 + i; }
        red_m[nt * TT + tt * 8 + j] = best;
        red_i[nt * TT + tt * 8 + j] = (unsigned)bi;
    }
    __syncthreads();
    // one thread per token: reduce over the 8 nt-groups (ascending => first max wins)
    float best = red_m[tid];
    unsigned bi = red_i[tid];
#pragma unroll
    for (int g = 1; g < 8; ++g) {
        float m = red_m[g * TT + tid];
        if (m > best) { best = m; bi = red_i[g * TT + tid]; }
    }
    idx[(size_t)(b * H_ + h) * S_ + s0 + tid] = bi;
}

// ---------------------------------------------------------------------------
// K4: v projection, bf16 MFMA 16x16x32. One block = 64 key rows x all 384 cols.
// vb[b*S+s][j] = bf16( sum_c key[s,c] * Wv[j,c] )
// ---------------------------------------------------------------------------
#define VA_STR 40
__global__ __launch_bounds__(256) void vproj_kernel(const float* __restrict__ key,
                                                    const float* __restrict__ Wv,
                                                    unsigned short* __restrict__ vb) {
    __shared__ unsigned short As[64 * VA_STR];   // [64 rows][40], valid [.][32]
    __shared__ unsigned short Bs[C_ * VA_STR];   // [384 rows][40]
    int tid = threadIdx.x;
    size_t m0 = (size_t)blockIdx.x * 64;
    int w = tid >> 6, l = tid & 63;
    int wm = w >> 1, wn = w & 1;
    int r = tid >> 2, qv = tid & 3;
    int lrow = (l >> 4) * 8;   // k-offset of A/B fragments
    int lm = l & 15;

    f32x4 accv[6][2][2];
#pragma unroll
    for (int j = 0; j < 6; ++j)
#pragma unroll
        for (int tm = 0; tm < 2; ++tm)
#pragma unroll
            for (int tn = 0; tn < 2; ++tn) accv[j][tm][tn] = (f32x4)0.f;

    for (int kc = 0; kc < C_; kc += 32) {
        __syncthreads();
        {   // stage A: key rows m0..m0+63, fp32 -> bf16
            const float* src = key + (m0 + r) * C_ + kc + qv * 8;
            float4 x0 = *(const float4*)(src);
            float4 x1 = *(const float4*)(src + 4);
            unsigned short tmp[8] = { f2bf(x0.x), f2bf(x0.y), f2bf(x0.z), f2bf(x0.w),
                                      f2bf(x1.x), f2bf(x1.y), f2bf(x1.z), f2bf(x1.w) };
            *(bf16x8*)&As[r * VA_STR + qv * 8] = *(bf16x8*)tmp;
        }
#pragma unroll
        for (int j = 0; j < 6; ++j) {   // stage B: Wv rows (all 384)
            const float* src = Wv + (size_t)(j * 64 + r) * C_ + kc + qv * 8;
            float4 x0 = *(const float4*)(src);
            float4 x1 = *(const float4*)(src + 4);
            unsigned short tmp[8] = { f2bf(x0.x), f2bf(x0.y), f2bf(x0.z), f2bf(x0.w),
                                      f2bf(x1.x), f2bf(x1.y), f2bf(x1.z), f2bf(x1.w) };
            *(bf16x8*)&Bs[(j * 64 + r) * VA_STR + qv * 8] = *(bf16x8*)tmp;
        }
        __syncthreads();
        bf16x8 af[2], bfr[6][2];
#pragma unroll
        for (int tm = 0; tm < 2; ++tm)
            af[tm] = *(bf16x8*)&As[(wm * 32 + tm * 16 + lm) * VA_STR + lrow];
#pragma unroll
        for (int j = 0; j < 6; ++j)
#pragma unroll
            for (int tn = 0; tn < 2; ++tn)
                bfr[j][tn] = *(bf16x8*)&Bs[(j * 64 + wn * 32 + tn * 16 + lm) * VA_STR + lrow];
#pragma unroll
        for (int j = 0; j < 6; ++j)
#pragma unroll
            for (int tm = 0; tm < 2; ++tm)
#pragma unroll
                for (int tn = 0; tn < 2; ++tn)
                    accv[j][tm][tn] = __builtin_amdgcn_mfma_f32_16x16x32_bf16(
                        af[tm], bfr[j][tn], accv[j][tm][tn], 0, 0, 0);
    }
    // epilogue: D layout col=lane&15, row=(lane>>4)*4+reg
    int drow = (l >> 4) * 4, dcol = l & 15;
#pragma unroll
    for (int j = 0; j < 6; ++j)
#pragma unroll
        for (int tm = 0; tm < 2; ++tm)
#pragma unroll
            for (int tn = 0; tn < 2; ++tn)
#pragma unroll
                for (int rr = 0; rr < 4; ++rr) {
                    size_t row = m0 + wm * 32 + tm * 16 + drow + rr;
                    int col = j * 64 + wn * 32 + tn * 16 + dcol;
                    vb[row * C_ + col] = f2bf(accv[j][tm][tn][rr]);
                }
}

// ---------------------------------------------------------------------------
// K5: scatter v rows into group accumulators (LDS histogram, stride-65 pad)
// ---------------------------------------------------------------------------
__global__ __launch_bounds__(256) void scatter_kernel(const unsigned short* __restrict__ vb,
                                                      const unsigned int* __restrict__ idx,
                                                      float* __restrict__ acc,
                                                      unsigned int* __restrict__ cnt) {
    __shared__ float accs[N_ * 65];
    __shared__ unsigned int cnts[N_];
    int tid = threadIdx.x;
    int h = blockIdx.y, b = blockIdx.z;
    int s0 = blockIdx.x * 512;
    for (int i = tid; i < N_ * 65; i += 256) accs[i] = 0.f;
    if (tid < N_) cnts[tid] = 0u;
    __syncthreads();
#pragma unroll
    for (int it = 0; it < 2; ++it) {
        int s = s0 + it * 256 + tid;
        unsigned g = idx[(size_t)(b * H_ + h) * S_ + s];
        const unsigned short* vrow = vb + ((size_t)b * S_ + s) * C_ + h * DH_;
        atomicAdd(&cnts[g], 1u);
#pragma unroll
        for (int d = 0; d < DH_; d += 4) {
            ushort4 v = *(const ushort4*)(vrow + d);
            atomicAdd(&accs[g * 65 + d + 0], bf2f(v.x));
            atomicAdd(&accs[g * 65 + d + 1], bf2f(v.y));
            atomicAdd(&accs[g * 65 + d + 2], bf2f(v.z));
            atomicAdd(&accs[g * 65 + d + 3], bf2f(v.w));
        }
    }
    __syncthreads();
    for (int i = tid; i < N_ * DH_; i += 256) {
        int g = i >> 6, d = i & 63;
        atomicAdd(&acc[((size_t)(b * H_ + h) * N_ + g) * DH_ + d], accs[g * 65 + d]);
    }
    if (tid < N_) atomicAdd(&cnt[(size_t)(b * H_ + h) * N_ + tid], cnts[tid]);
}

// ---------------------------------------------------------------------------
// K6: out[b,n,j] = sum_c (acc[b,h,n,d]/(cnt+1)) * Wp[j,c] + bp[j]
// ---------------------------------------------------------------------------
__global__ __launch_bounds__(384) void out_kernel(const float* __restrict__ acc,
                                                  const unsigned int* __restrict__ cnt,
                                                  const float* __restrict__ Wp,
                                                  const float* __restrict__ bp,
                                                  float* __restrict__ out) {
    __shared__ float vals[C_];
    int bn = blockIdx.x;
    int b = bn >> 6, n = bn & 63;
    int t = threadIdx.x;
    int h = t >> 6, d = t & 63;
    size_t gi = (size_t)(b * H_ + h) * N_ + n;
    vals[t] = acc[gi * DH_ + d] / ((float)cnt[gi] + 1.0f);
    __syncthreads();
    const float4* w4 = (const float4*)(Wp + (size_t)t * C_);
    const float4* v4 = (const float4*)vals;
    float s = bp[t];
#pragma unroll 8
    for (int i = 0; i < C_ / 4; ++i) {
        float4 a = v4[i]; float4 w = w4[i];
        s += a.x * w.x + a.y * w.y + a.z * w.z + a.w * w.w;
    }
    out[(size_t)bn * C_ + t] = s;
}

// ---------------------------------------------------------------------------
extern "C" void kernel_launch(void* const* d_in, const int* in_sizes, int n_in,
                              void* d_out, int out_size, void* d_ws, size_t ws_size,
                              hipStream_t stream) {
    (void)in_sizes; (void)n_in; (void)out_size; (void)ws_size;
    const float* query = (const float*)d_in[0];
    const float* key   = (const float*)d_in[1];
    const float* Wq    = (const float*)d_in[2];
    const float* Wk    = (const float*)d_in[3];
    const float* Wv    = (const float*)d_in[4];
    const float* Wp    = (const float*)d_in[5];
    const float* bp    = (const float*)d_in[6];
    float* out = (float*)d_out;

    char* ws = (char*)d_ws;
    size_t off = 0;
    unsigned short* vb = (unsigned short*)(ws + off); off += (size_t)B_ * S_ * C_ * 2;  // 50.3 MB
    float* qk = (float*)(ws + off);          off += (size_t)B_ * H_ * N_ * C_ * 4;      //  9.4 MB
    float* q  = (float*)(ws + off);          off += (size_t)B_ * N_ * C_ * 4;           //  1.6 MB
    unsigned int* idx = (unsigned int*)(ws + off); off += (size_t)B_ * H_ * S_ * 4;     //  1.6 MB
    float* acc = (float*)(ws + off);         off += (size_t)B_ * H_ * N_ * DH_ * 4;     //  1.6 MB
    unsigned int* cnt = (unsigned int*)(ws + off); off += (size_t)B_ * H_ * N_ * 4;

    // zero the scatter accumulators (acc + cnt are adjacent)
    hipMemsetAsync(acc, 0, (size_t)B_ * H_ * N_ * DH_ * 4 + (size_t)B_ * H_ * N_ * 4, stream);

    qproj_kernel<<<B_ * N_, 384, 0, stream>>>(query, Wq, q);
    qk_kernel<<<dim3(N_, H_, B_), 384, 0, stream>>>(q, Wk, qk);
    attn_kernel<<<dim3(S_ / TT, H_, B_), 256, 0, stream>>>(qk, key, idx);
    vproj_kernel<<<B_ * S_ / 64, 256, 0, stream>>>(key, Wv, vb);
    scatter_kernel<<<dim3(S_ / 512, H_, B_), 256, 0, stream>>>(vb, idx, acc, cnt);
    out_kernel<<<B_ * N_, 384, 0, stream>>>(acc, cnt, Wp, bp, out);
}

// Round 2
// 600.603 us; speedup vs baseline: 1.1432x; 1.1432x over previous
//
#include <hip/hip_runtime.h>
#include <hip/hip_bf16.h>
#include <stdint.h>

#define B_ 16
#define N_ 64
#define S_ 4096
#define C_ 384
#define H_ 6
#define DH_ 64
#define SCALE_ 0.125f
#define TAU_ 4e-3f
#define LISTCAP 262144

typedef __attribute__((ext_vector_type(8))) short bf16x8;
typedef __attribute__((ext_vector_type(4))) float f32x4;

static __device__ __forceinline__ unsigned short f2bf(float x) {
    union { float f; unsigned u; } v; v.f = x;
    unsigned r = v.u + 0x7FFFu + ((v.u >> 16) & 1u);
    return (unsigned short)(r >> 16);
}
static __device__ __forceinline__ float bf2f(unsigned short b) {
    union { unsigned u; float f; } v; v.u = ((unsigned)b) << 16; return v.f;
}

// async global->LDS, 16B per lane; LDS dest must be wave-uniform base (+lane*16 implied)
static __device__ __forceinline__ void gl_lds16(const void* g, void* l) {
    __builtin_amdgcn_global_load_lds(
        (const __attribute__((address_space(1))) unsigned int*)g,
        (__attribute__((address_space(3))) unsigned int*)l, 16, 0, 0);
}

// ---------------------------------------------------------------------------
// K0: prep — key -> khi/klo (bf16 hi + bf16 residual), Wv -> bf16
// ---------------------------------------------------------------------------
__global__ __launch_bounds__(256) void prep_kernel(const float* __restrict__ key,
                                                   const float* __restrict__ Wv,
                                                   unsigned short* __restrict__ khi,
                                                   unsigned short* __restrict__ klo,
                                                   unsigned short* __restrict__ wvb) {
    size_t gid = (size_t)blockIdx.x * 256 + threadIdx.x;
    const size_t nkey8 = (size_t)B_ * S_ * C_ / 8;   // 3,145,728
    if (gid < nkey8) {
        size_t base = gid * 8;
        float4 x0 = *(const float4*)(key + base);
        float4 x1 = *(const float4*)(key + base + 4);
        float xs[8] = { x0.x, x0.y, x0.z, x0.w, x1.x, x1.y, x1.z, x1.w };
        unsigned short hi[8], lo[8];
#pragma unroll
        for (int i = 0; i < 8; ++i) {
            hi[i] = f2bf(xs[i]);
            lo[i] = f2bf(xs[i] - bf2f(hi[i]));
        }
        *(bf16x8*)(khi + base) = *(bf16x8*)hi;
        *(bf16x8*)(klo + base) = *(bf16x8*)lo;
    } else {
        size_t g2 = gid - nkey8;
        if (g2 < (size_t)C_ * C_ / 8) {
            size_t base = g2 * 8;
            float4 x0 = *(const float4*)(Wv + base);
            float4 x1 = *(const float4*)(Wv + base + 4);
            float xs[8] = { x0.x, x0.y, x0.z, x0.w, x1.x, x1.y, x1.z, x1.w };
            unsigned short hi[8];
#pragma unroll
            for (int i = 0; i < 8; ++i) hi[i] = f2bf(xs[i]);
            *(bf16x8*)(wvb + base) = *(bf16x8*)hi;
        }
    }
}

// ---------------------------------------------------------------------------
// K1: q[b,n,c] = SCALE * query[b,n,:] . Wq[c,:]   (fp32 exact)
// ---------------------------------------------------------------------------
__global__ __launch_bounds__(384) void qproj_kernel(const float* __restrict__ query,
                                                    const float* __restrict__ Wq,
                                                    float* __restrict__ qout) {
    __shared__ float row[C_];
    int bn = blockIdx.x;
    int t = threadIdx.x;
    row[t] = query[(size_t)bn * C_ + t];
    __syncthreads();
    const float4* w4 = (const float4*)(Wq + (size_t)t * C_);
    const float4* r4 = (const float4*)row;
    float acc = 0.f;
#pragma unroll 8
    for (int i = 0; i < C_ / 4; ++i) {
        float4 a = r4[i]; float4 w = w4[i];
        acc += a.x * w.x + a.y * w.y + a.z * w.z + a.w * w.w;
    }
    qout[(size_t)bn * C_ + t] = acc * SCALE_;
}

// ---------------------------------------------------------------------------
// K2: qk[b,h,n,c] = q[b,n,h*64:+64] . Wk[h*64:+64, c]  (fp32) + bf16 hi/lo split
// ---------------------------------------------------------------------------
__global__ __launch_bounds__(384) void qk_kernel(const float* __restrict__ q,
                                                 const float* __restrict__ Wk,
                                                 float* __restrict__ qk,
                                                 unsigned short* __restrict__ qkhi,
                                                 unsigned short* __restrict__ qklo) {
    __shared__ float qh[DH_];
    int n = blockIdx.x, h = blockIdx.y, b = blockIdx.z;
    int t = threadIdx.x;
    if (t < DH_) qh[t] = q[((size_t)(b * N_ + n)) * C_ + h * DH_ + t];
    __syncthreads();
    float acc = 0.f;
    const float* wrow = Wk + (size_t)h * DH_ * C_ + t;
#pragma unroll 8
    for (int d = 0; d < DH_; ++d) acc += qh[d] * wrow[(size_t)d * C_];
    size_t o = ((size_t)(b * H_ + h) * N_ + n) * C_ + t;
    qk[o] = acc;
    unsigned short hi = f2bf(acc);
    qkhi[o] = hi;
    qklo[o] = f2bf(acc - bf2f(hi));
}

// ---------------------------------------------------------------------------
// K3: logits via 3-pass bf16 MFMA (hi*hi + hi*lo + lo*hi), per-column argmax
//     with top-2 margin; near-ties flagged for exact fp32 fixup.
// Block: 256 thr (4 waves), tile = 64 n-rows x 256 tokens, K=384 in 12 chunks.
// wave (wm,wn): m-tiles {wm*2,wm*2+1}, n-tiles wn*8..wn*8+7
// ---------------------------------------------------------------------------
__global__ __launch_bounds__(256) void attn_kernel(const unsigned short* __restrict__ qkhi,
                                                   const unsigned short* __restrict__ qklo,
                                                   const unsigned short* __restrict__ khi,
                                                   const unsigned short* __restrict__ klo,
                                                   unsigned int* __restrict__ idx,
                                                   unsigned int* __restrict__ flag_cnt,
                                                   unsigned int* __restrict__ flag_list) {
    __shared__ __align__(16) unsigned short sAhi[64 * 32];
    __shared__ __align__(16) unsigned short sAlo[64 * 32];
    __shared__ __align__(16) unsigned short sBhi[256 * 32];
    __shared__ __align__(16) unsigned short sBlo[256 * 32];
    int tid = threadIdx.x;
    int w = tid >> 6, l = tid & 63;
    int wm = w >> 1, wn = w & 1;
    int q4 = l >> 4, lm = l & 15;
    int s0 = blockIdx.x * 256;
    int h = blockIdx.y, b = blockIdx.z;
    size_t kbK = ((size_t)b * S_ + s0) * C_;
    size_t kbA = (size_t)(b * H_ + h) * N_ * C_;
    int trow16 = l >> 2;          // 0..15 (token/row within 16-row staging block)
    int tquart = (l & 3) * 8;     // k-quarter (8 bf16 = 16B)

    f32x4 acc[2][8];
#pragma unroll
    for (int tm = 0; tm < 2; ++tm)
#pragma unroll
        for (int nt = 0; nt < 8; ++nt) acc[tm][nt] = (f32x4)0.f;

    for (int kc = 0; kc < C_; kc += 32) {
        __syncthreads();
#pragma unroll
        for (int i = 0; i < 10; ++i) {
            int gid = w * 10 + i;
            if (gid < 16) {
                gl_lds16(khi + kbK + (size_t)(gid * 16 + trow16) * C_ + kc + tquart,
                         (char*)sBhi + gid * 1024);
            } else if (gid < 32) {
                int g2 = gid - 16;
                gl_lds16(klo + kbK + (size_t)(g2 * 16 + trow16) * C_ + kc + tquart,
                         (char*)sBlo + g2 * 1024);
            } else if (gid < 36) {
                int g2 = gid - 32;
                gl_lds16(qkhi + kbA + (size_t)(g2 * 16 + trow16) * C_ + kc + tquart,
                         (char*)sAhi + g2 * 1024);
            } else {
                int g2 = gid - 36;
                gl_lds16(qklo + kbA + (size_t)(g2 * 16 + trow16) * C_ + kc + tquart,
                         (char*)sAlo + g2 * 1024);
            }
        }
        __syncthreads();
        bf16x8 ah[2], al[2];
#pragma unroll
        for (int tm = 0; tm < 2; ++tm) {
            int ar = (wm * 32 + tm * 16 + lm) * 32 + q4 * 8;
            ah[tm] = *(const bf16x8*)&sAhi[ar];
            al[tm] = *(const bf16x8*)&sAlo[ar];
        }
#pragma unroll
        for (int nt = 0; nt < 8; ++nt) {
            int nr = ((wn * 8 + nt) * 16 + lm) * 32 + q4 * 8;
            bf16x8 bh = *(const bf16x8*)&sBhi[nr];
            bf16x8 bl = *(const bf16x8*)&sBlo[nr];
#pragma unroll
            for (int tm = 0; tm < 2; ++tm) {
                acc[tm][nt] = __builtin_amdgcn_mfma_f32_16x16x32_bf16(ah[tm], bh, acc[tm][nt], 0, 0, 0);
                acc[tm][nt] = __builtin_amdgcn_mfma_f32_16x16x32_bf16(ah[tm], bl, acc[tm][nt], 0, 0, 0);
                acc[tm][nt] = __builtin_amdgcn_mfma_f32_16x16x32_bf16(al[tm], bh, acc[tm][nt], 0, 0, 0);
            }
        }
    }
    __syncthreads();   // all waves done reading staged tiles; reuse sBhi for reduction

    float* rm1 = (float*)sBhi;            // [2][256]
    float* rm2 = rm1 + 512;
    int* ri1 = (int*)(rm2 + 512);
    int* ri2 = ri1 + 512;

#pragma unroll
    for (int nt = 0; nt < 8; ++nt) {
        float m1 = -3.4e38f, m2 = -3.4e38f; int i1 = 0, i2 = 0;
#pragma unroll
        for (int tm = 0; tm < 2; ++tm)
#pragma unroll
            for (int r = 0; r < 4; ++r) {
                float v = acc[tm][nt][r];
                int row = wm * 32 + tm * 16 + q4 * 4 + r;
                if (v > m1) { m2 = m1; i2 = i1; m1 = v; i1 = row; }
                else if (v > m2) { m2 = v; i2 = row; }
            }
        // butterfly over the 4 lanes sharing this column (stride 16)
#pragma unroll
        for (int off = 16; off < 64; off <<= 1) {
            float om1 = __shfl_xor(m1, off), om2 = __shfl_xor(m2, off);
            int oi1 = __shfl_xor(i1, off), oi2 = __shfl_xor(i2, off);
            bool take = (om1 > m1) || (om1 == m1 && oi1 < i1);
            float w1 = take ? om1 : m1; int wi1 = take ? oi1 : i1;
            float l1 = take ? m1 : om1; int li1 = take ? i1 : oi1;
            float s2 = m2; int si2 = i2;
            if (om2 > s2) { s2 = om2; si2 = oi2; }
            if (l1 > s2) { s2 = l1; si2 = li1; }
            m1 = w1; i1 = wi1; m2 = s2; i2 = si2;
        }
        if (q4 == 0) {
            int cw = (wn * 8 + nt) * 16 + lm;
            rm1[wm * 256 + cw] = m1; rm2[wm * 256 + cw] = m2;
            ri1[wm * 256 + cw] = i1; ri2[wm * 256 + cw] = i2;
        }
    }
    __syncthreads();
    // final merge (wm0 rows 0..31 < wm1 rows 32..63, so plain strict > keeps first-index)
    float a1 = rm1[tid], a2 = rm2[tid];
    int ai1 = ri1[tid], ai2 = ri2[tid];
    float b1 = rm1[256 + tid], b2 = rm2[256 + tid];
    int bi1 = ri1[256 + tid], bi2 = ri2[256 + tid];
    float w1, s2; int wi1, wi2;
    if (b1 > a1) { w1 = b1; wi1 = bi1; s2 = a1; wi2 = ai1; if (b2 > s2) { s2 = b2; wi2 = bi2; } }
    else         { w1 = a1; wi1 = ai1; s2 = a2; wi2 = ai2; if (b1 > s2) { s2 = b1; wi2 = bi1; } }
    idx[(size_t)(b * H_ + h) * S_ + s0 + tid] = (unsigned)wi1;
    if (w1 - s2 < TAU_) {
        unsigned p = atomicAdd(flag_cnt, 1u);
        if (p < LISTCAP) {
            unsigned tok = (unsigned)((b * H_ + h) * S_ + s0 + tid);
            flag_list[p] = tok | ((unsigned)wi1 << 19) | ((unsigned)wi2 << 25);
        }
    }
}

// ---------------------------------------------------------------------------
// K4: fixup — exact fp32 recompute of the two candidate rows for near-ties
// one 64-lane wave per flagged token; lanes 0-31: row i1, lanes 32-63: row i2
// ---------------------------------------------------------------------------
__global__ __launch_bounds__(256) void fixup_kernel(const float* __restrict__ qk,
                                                    const float* __restrict__ key,
                                                    const unsigned int* __restrict__ flag_list,
                                                    const unsigned int* __restrict__ flag_cnt,
                                                    unsigned int* __restrict__ idx) {
    int w = threadIdx.x >> 6, l = threadIdx.x & 63;
    unsigned total = flag_cnt[0];
    if (total > LISTCAP) total = LISTCAP;
    for (unsigned t = blockIdx.x * 4 + w; t < total; t += gridDim.x * 4) {
        unsigned e = flag_list[t];
        unsigned tok = e & 0x7FFFFu;
        int i1 = (int)((e >> 19) & 63u), i2 = (int)((e >> 25) & 63u);
        unsigned bh = tok >> 12;
        unsigned s = tok & 4095u;
        unsigned bb = bh / H_;
        int l32 = l & 31;
        const float* qrow = qk + ((size_t)bh * N_ + (l < 32 ? i1 : i2)) * C_ + l32 * 12;
        const float* krow = key + ((size_t)bb * S_ + s) * C_ + l32 * 12;
        float sum = 0.f;
#pragma unroll
        for (int c = 0; c < 12; ++c) sum += qrow[c] * krow[c];
#pragma unroll
        for (int off = 1; off < 32; off <<= 1) sum += __shfl_xor(sum, off);
        float d1 = __shfl(sum, 0);
        float d2 = __shfl(sum, 32);
        int win = (d2 > d1 || (d2 == d1 && i2 < i1)) ? i2 : i1;
        if (l == 0) idx[(size_t)bh * S_ + s] = (unsigned)win;
    }
}

// ---------------------------------------------------------------------------
// K5: v projection, bf16 MFMA, staged via global_load_lds (khi + Wvb inputs)
// block = 64 key rows x all 384 cols
// ---------------------------------------------------------------------------
__global__ __launch_bounds__(256) void vproj_kernel(const unsigned short* __restrict__ khi,
                                                    const unsigned short* __restrict__ wvb,
                                                    unsigned short* __restrict__ vb) {
    __shared__ __align__(16) unsigned short sA[64 * 32];
    __shared__ __align__(16) unsigned short sB[C_ * 32];
    int tid = threadIdx.x;
    size_t m0 = (size_t)blockIdx.x * 64;
    int w = tid >> 6, l = tid & 63;
    int wm = w >> 1, wn = w & 1;
    int q4 = l >> 4, lm = l & 15;
    int trow16 = l >> 2;
    int tquart = (l & 3) * 8;

    f32x4 accv[6][2][2];
#pragma unroll
    for (int j = 0; j < 6; ++j)
#pragma unroll
        for (int tm = 0; tm < 2; ++tm)
#pragma unroll
            for (int tn = 0; tn < 2; ++tn) accv[j][tm][tn] = (f32x4)0.f;

    for (int kc = 0; kc < C_; kc += 32) {
        __syncthreads();
#pragma unroll
        for (int i = 0; i < 7; ++i) {
            int gid = w * 7 + i;
            if (gid < 24) {
                gl_lds16(wvb + (size_t)(gid * 16 + trow16) * C_ + kc + tquart,
                         (char*)sB + gid * 1024);
            } else {
                int g2 = gid - 24;
                gl_lds16(khi + (m0 + g2 * 16 + trow16) * C_ + kc + tquart,
                         (char*)sA + g2 * 1024);
            }
        }
        __syncthreads();
        bf16x8 af[2], bfr[6][2];
#pragma unroll
        for (int tm = 0; tm < 2; ++tm)
            af[tm] = *(const bf16x8*)&sA[(wm * 32 + tm * 16 + lm) * 32 + q4 * 8];
#pragma unroll
        for (int j = 0; j < 6; ++j)
#pragma unroll
            for (int tn = 0; tn < 2; ++tn)
                bfr[j][tn] = *(const bf16x8*)&sB[(j * 64 + wn * 32 + tn * 16 + lm) * 32 + q4 * 8];
#pragma unroll
        for (int j = 0; j < 6; ++j)
#pragma unroll
            for (int tm = 0; tm < 2; ++tm)
#pragma unroll
                for (int tn = 0; tn < 2; ++tn)
                    accv[j][tm][tn] = __builtin_amdgcn_mfma_f32_16x16x32_bf16(
                        af[tm], bfr[j][tn], accv[j][tm][tn], 0, 0, 0);
    }
    int drow = (l >> 4) * 4, dcol = l & 15;
#pragma unroll
    for (int j = 0; j < 6; ++j)
#pragma unroll
        for (int tm = 0; tm < 2; ++tm)
#pragma unroll
            for (int tn = 0; tn < 2; ++tn)
#pragma unroll
                for (int rr = 0; rr < 4; ++rr) {
                    size_t row = m0 + wm * 32 + tm * 16 + drow + rr;
                    int col = j * 64 + wn * 32 + tn * 16 + dcol;
                    vb[row * C_ + col] = f2bf(accv[j][tm][tn][rr]);
                }
}

// ---------------------------------------------------------------------------
// K6: scatter v rows into group accumulators; lane-rotated channel order so
// same-group lanes hit distinct LDS addresses (no same-address serialization)
// ---------------------------------------------------------------------------
__global__ __launch_bounds__(256) void scatter_kernel(const unsigned short* __restrict__ vb,
                                                      const unsigned int* __restrict__ idx,
                                                      float* __restrict__ acc,
                                                      unsigned int* __restrict__ cnt) {
    __shared__ float accs[N_ * 65];
    __shared__ unsigned int cnts[N_];
    int tid = threadIdx.x;
    int h = blockIdx.y, b = blockIdx.z;
    int s0 = blockIdx.x * 512;
    for (int i = tid; i < N_ * 65; i += 256) accs[i] = 0.f;
    if (tid < N_) cnts[tid] = 0u;
    __syncthreads();
#pragma unroll
    for (int it = 0; it < 2; ++it) {
        int s = s0 + it * 256 + tid;
        unsigned g = idx[(size_t)(b * H_ + h) * S_ + s];
        const unsigned short* vrow = vb + ((size_t)b * S_ + s) * C_ + h * DH_;
        atomicAdd(&cnts[g], 1u);
#pragma unroll
        for (int jj = 0; jj < 16; ++jj) {
            int c4 = ((jj + (tid & 15)) & 15) * 4;
            ushort4 v = *(const ushort4*)(vrow + c4);
            atomicAdd(&accs[g * 65 + c4 + 0], bf2f(v.x));
            atomicAdd(&accs[g * 65 + c4 + 1], bf2f(v.y));
            atomicAdd(&accs[g * 65 + c4 + 2], bf2f(v.z));
            atomicAdd(&accs[g * 65 + c4 + 3], bf2f(v.w));
        }
    }
    __syncthreads();
    for (int i = tid; i < N_ * DH_; i += 256) {
        int g = i >> 6, d = i & 63;
        atomicAdd(&acc[((size_t)(b * H_ + h) * N_ + g) * DH_ + d], accs[g * 65 + d]);
    }
    if (tid < N_) atomicAdd(&cnt[(size_t)(b * H_ + h) * N_ + tid], cnts[tid]);
}

// ---------------------------------------------------------------------------
// K7: out[b,n,j] = sum_c (acc[b,h,n,d]/(cnt+1)) * Wp[j,c] + bp[j]
// ---------------------------------------------------------------------------
__global__ __launch_bounds__(384) void out_kernel(const float* __restrict__ acc,
                                                  const unsigned int* __restrict__ cnt,
                                                  const float* __restrict__ Wp,
                                                  const float* __restrict__ bp,
                                                  float* __restrict__ out) {
    __shared__ float vals[C_];
    int bn = blockIdx.x;
    int b = bn >> 6, n = bn & 63;
    int t = threadIdx.x;
    int h = t >> 6, d = t & 63;
    size_t gi = (size_t)(b * H_ + h) * N_ + n;
    vals[t] = acc[gi * DH_ + d] / ((float)cnt[gi] + 1.0f);
    __syncthreads();
    const float4* w4 = (const float4*)(Wp + (size_t)t * C_);
    const float4* v4 = (const float4*)vals;
    float s = bp[t];
#pragma unroll 8
    for (int i = 0; i < C_ / 4; ++i) {
        float4 a = v4[i]; float4 w = w4[i];
        s += a.x * w.x + a.y * w.y + a.z * w.z + a.w * w.w;
    }
    out[(size_t)bn * C_ + t] = s;
}

// ---------------------------------------------------------------------------
extern "C" void kernel_launch(void* const* d_in, const int* in_sizes, int n_in,
                              void* d_out, int out_size, void* d_ws, size_t ws_size,
                              hipStream_t stream) {
    (void)in_sizes; (void)n_in; (void)out_size; (void)ws_size;
    const float* query = (const float*)d_in[0];
    const float* key   = (const float*)d_in[1];
    const float* Wq    = (const float*)d_in[2];
    const float* Wk    = (const float*)d_in[3];
    const float* Wv    = (const float*)d_in[4];
    const float* Wp    = (const float*)d_in[5];
    const float* bp    = (const float*)d_in[6];
    float* out = (float*)d_out;

    char* ws = (char*)d_ws;
    size_t off = 0;
    unsigned short* vb   = (unsigned short*)(ws + off); off += (size_t)B_ * S_ * C_ * 2;      // 50.3 MB
    unsigned short* khi  = (unsigned short*)(ws + off); off += (size_t)B_ * S_ * C_ * 2;      // 50.3 MB
    unsigned short* klo  = (unsigned short*)(ws + off); off += (size_t)B_ * S_ * C_ * 2;      // 50.3 MB
    float* qk            = (float*)(ws + off);          off += (size_t)B_ * H_ * N_ * C_ * 4; //  9.4 MB
    unsigned short* qkhi = (unsigned short*)(ws + off); off += (size_t)B_ * H_ * N_ * C_ * 2; //  4.7 MB
    unsigned short* qklo = (unsigned short*)(ws + off); off += (size_t)B_ * H_ * N_ * C_ * 2; //  4.7 MB
    float* q             = (float*)(ws + off);          off += (size_t)B_ * N_ * C_ * 4;      //  1.6 MB
    unsigned int* idx    = (unsigned int*)(ws + off);   off += (size_t)B_ * H_ * S_ * 4;      //  1.6 MB
    unsigned short* wvb  = (unsigned short*)(ws + off); off += (size_t)C_ * C_ * 2;           //  0.3 MB
    float* acc           = (float*)(ws + off);          off += (size_t)B_ * H_ * N_ * DH_ * 4;//  1.6 MB
    unsigned int* cnt    = (unsigned int*)(ws + off);   off += (size_t)B_ * H_ * N_ * 4;
    unsigned int* fcnt   = (unsigned int*)(ws + off);   off += 256;
    unsigned int* flist  = (unsigned int*)(ws + off);   off += (size_t)LISTCAP * 4;           //  1.0 MB

    // zero acc + cnt + flag counter (contiguous)
    hipMemsetAsync(acc, 0,
                   (size_t)B_ * H_ * N_ * DH_ * 4 + (size_t)B_ * H_ * N_ * 4 + 256, stream);

    prep_kernel<<<12360, 256, 0, stream>>>(key, Wv, khi, klo, wvb);
    qproj_kernel<<<B_ * N_, 384, 0, stream>>>(query, Wq, q);
    qk_kernel<<<dim3(N_, H_, B_), 384, 0, stream>>>(q, Wk, qk, qkhi, qklo);
    attn_kernel<<<dim3(S_ / 256, H_, B_), 256, 0, stream>>>(qkhi, qklo, khi, klo, idx, fcnt, flist);
    vproj_kernel<<<B_ * S_ / 64, 256, 0, stream>>>(khi, wvb, vb);
    fixup_kernel<<<256, 256, 0, stream>>>(qk, key, flist, fcnt, idx);
    scatter_kernel<<<dim3(S_ / 512, H_, B_), 256, 0, stream>>>(vb, idx, acc, cnt);
    out_kernel<<<B_ * N_, 384, 0, stream>>>(acc, cnt, Wp, bp, out);
}